// Round 4
// baseline (221.094 us; speedup 1.0000x reference)
//
#include <hip/hip_runtime.h>
#include <hip/hip_bf16.h>

#define NB 64
#define BATCHES 16
#define ELEMS_PER_BATCH (1024 * 1024)
#define CHUNKS 128                               // blocks per batch
#define CHUNK_ELEMS (ELEMS_PER_BATCH / CHUNKS)   // 8192
#define EPS 1e-8f

__global__ void mi_zero_kernel(unsigned int* __restrict__ hist) {
    int i = threadIdx.x;
    if (i < BATCHES * NB) hist[i] = 0u;
}

// Ballot histogram: no LDS in the hot loop. Each wave keeps 64 uniform
// counters (SGPRs). For each element slot, one v_cmp per bin (inline-const
// operand) -> 64-bit ballot -> s_bcnt1 -> s_add on the scalar pipe, which
// co-issues with the VALU compares. ~2 VALU cycles per element per wave.
__global__ __launch_bounds__(256) void mi_hist_kernel(const float* __restrict__ x,
                                                      const float* __restrict__ y,
                                                      unsigned int* __restrict__ hist) {
    const int tid  = threadIdx.x;
    const int lane = tid & 63;

    const int b     = blockIdx.y;
    const long base = (long)b * ELEMS_PER_BATCH + (long)blockIdx.x * CHUNK_ELEMS;
    const float4* __restrict__ x4 = (const float4*)(x + base);
    const float4* __restrict__ y4 = (const float4*)(y + base);
    const int n4 = CHUNK_ELEMS / 4;              // 2048 float4 per block

    unsigned int cnt[NB];
    #pragma unroll
    for (int i = 0; i < NB; ++i) cnt[i] = 0u;

    for (int i = tid; i < n4; i += 256) {
        float4 xv = x4[i];
        float4 yv = y4[i];
        unsigned int idx[4];
        #pragma unroll
        for (int c = 0; c < 4; ++c) {
            float xc = (&xv.x)[c];
            float yc = (&yv.x)[c];
            // mul then add with intermediate rounding — matches numpy (no FMA)
            float v = __fadd_rn(__fmul_rn(xc, 64.0f), yc);
            int t = (int)v;                       // v >= 0 here, floor == trunc
            if (t > NB - 1) t = NB - 1;           // v == 64 -> last bin
            // histc drops v outside [0, 64]; v in (64, 65) must NOT clamp in
            idx[c] = (v >= 0.0f && v <= 64.0f) ? (unsigned int)t : 255u;
        }
        #pragma unroll
        for (int bin = 0; bin < NB; ++bin) {
            unsigned int s = 0;
            #pragma unroll
            for (int c = 0; c < 4; ++c)
                s += (unsigned int)__popcll(__ballot(idx[c] == (unsigned int)bin));
            cnt[bin] += s;
        }
    }

    // Epilogue: lane k takes cnt[k] (uniform -> 64 selects, one-time cost),
    // then one 64-lane global atomic per wave.
    unsigned int mine = 0;
    #pragma unroll
    for (int bin = 0; bin < NB; ++bin)
        mine = (lane == bin) ? cnt[bin] : mine;

    atomicAdd(&hist[b * NB + lane], mine);
}

// One block: 16 waves, wave b handles batch b, lane k handles bin k.
__global__ __launch_bounds__(1024) void mi_final_kernel(const unsigned int* __restrict__ hist,
                                                        float* __restrict__ out) {
    const int tid = threadIdx.x;
    const int b   = tid >> 6;
    const int k   = tid & 63;

    float h = (float)hist[b * NB + k];

    // wave-reduce: total count for this batch
    float s = h;
    #pragma unroll
    for (int off = 32; off >= 1; off >>= 1) s += __shfl_xor(s, off, 64);

    float jp = h / s + EPS;

    // p = sum over bins of jp (reference sums joint_prob, ~1 + 64*EPS)
    float p = jp;
    #pragma unroll
    for (int off = 32; off >= 1; off >>= 1) p += __shfl_xor(p, off, 64);

    float term = jp * logf(jp / (p * p));
    float t = term;
    #pragma unroll
    for (int off = 32; off >= 1; off >>= 1) t += __shfl_xor(t, off, 64);

    __shared__ float mi[BATCHES];
    if (k == 0) mi[b] = t;
    __syncthreads();

    if (tid == 0) {
        float acc = 0.0f;
        #pragma unroll
        for (int i = 0; i < BATCHES; ++i) acc += mi[i];
        *out = -acc / (float)BATCHES;
    }
}

extern "C" void kernel_launch(void* const* d_in, const int* in_sizes, int n_in,
                              void* d_out, int out_size, void* d_ws, size_t ws_size,
                              hipStream_t stream) {
    const float* x = (const float*)d_in[0];
    const float* y = (const float*)d_in[1];
    float* out = (float*)d_out;
    unsigned int* hist = (unsigned int*)d_ws;

    mi_zero_kernel<<<1, 1024, 0, stream>>>(hist);

    dim3 grid(CHUNKS, BATCHES);
    mi_hist_kernel<<<grid, 256, 0, stream>>>(x, y, hist);

    mi_final_kernel<<<1, 1024, 0, stream>>>(hist, out);
}

// Round 5
// 184.223 us; speedup vs baseline: 1.2001x; 1.2001x over previous
//
#include <hip/hip_runtime.h>
#include <hip/hip_bf16.h>

#define NB 64
#define BATCHES 16
#define ELEMS_PER_BATCH (1024 * 1024)
#define CHUNKS 128                               // blocks per batch
#define CHUNK_ELEMS (ELEMS_PER_BATCH / CHUNKS)   // 8192
#define EPS 1e-8f

__global__ void mi_zero_kernel(unsigned int* __restrict__ hist) {
    int i = threadIdx.x;
    if (i < BATCHES * NB) hist[i] = 0u;
}

// Per-lane-private packed histograms (round-3 scheme: 0 conflicts, correct),
// plus explicit 2x4 unroll: 8 dwordx4 loads in flight before consumption to
// hide memory latency (round-3 issued only 2 per vmcnt round-trip).
__global__ __launch_bounds__(256) void mi_hist_kernel(const float* __restrict__ x,
                                                      const float* __restrict__ y,
                                                      unsigned int* __restrict__ hist) {
    __shared__ unsigned int lh[4][NB / 2][64];   // 32 KB
    __shared__ unsigned int rb[4][NB];

    const int tid  = threadIdx.x;
    const int wave = tid >> 6;
    const int lane = tid & 63;

    for (int i = tid; i < 4 * (NB / 2) * 64 + 4 * NB; i += 256)
        ((unsigned int*)lh)[i] = 0u;
    __syncthreads();

    const int b     = blockIdx.y;
    const long base = (long)b * ELEMS_PER_BATCH + (long)blockIdx.x * CHUNK_ELEMS;
    const float4* __restrict__ x4 = (const float4*)(x + base);
    const float4* __restrict__ y4 = (const float4*)(y + base);

    unsigned int* __restrict__ myrow = &lh[wave][0][lane];

    // 2048 float4 per array per block; 256 threads -> 8 slots/thread; 2 halves of 4.
    #pragma unroll
    for (int half = 0; half < 2; ++half) {
        float4 xv[4], yv[4];
        #pragma unroll
        for (int k = 0; k < 4; ++k) {
            int i = tid + (half * 4 + k) * 256;
            xv[k] = x4[i];
            yv[k] = y4[i];
        }
        #pragma unroll
        for (int k = 0; k < 4; ++k) {
            #pragma unroll
            for (int c = 0; c < 4; ++c) {
                float xc = (&xv[k].x)[c];
                float yc = (&yv[k].x)[c];
                float v = __fadd_rn(__fmul_rn(xc, 64.0f), yc);   // no FMA: match numpy
                if (v >= 0.0f && v <= 64.0f) {
                    int idx = (int)v;                 // v >= 0: floor == trunc
                    if (idx > NB - 1) idx = NB - 1;   // v == 64 -> last bin
                    atomicAdd(myrow + (idx >> 1) * 64, 1u << ((idx & 1) << 4));
                }
            }
        }
    }
    __syncthreads();

    if (lane < 32) {
        unsigned int lo = 0, hi = 0;
        #pragma unroll
        for (int j = 0; j < 64; ++j) {
            unsigned int vv = lh[wave][lane][(j + lane) & 63];
            lo += vv & 0xffffu;
            hi += vv >> 16;
        }
        rb[wave][2 * lane]     = lo;
        rb[wave][2 * lane + 1] = hi;
    }
    __syncthreads();

    if (tid < NB) {
        unsigned int s = rb[0][tid] + rb[1][tid] + rb[2][tid] + rb[3][tid];
        atomicAdd(&hist[b * NB + tid], s);
    }
}

// ABLATION 1: identical loads + bin compute, no LDS. Measures the memory
// floor of this access pattern. asm sink keeps everything live (rule #17).
__global__ __launch_bounds__(256) void mi_ablate_loads(const float* __restrict__ x,
                                                       const float* __restrict__ y) {
    const int tid   = threadIdx.x;
    const int b     = blockIdx.y;
    const long base = (long)b * ELEMS_PER_BATCH + (long)blockIdx.x * CHUNK_ELEMS;
    const float4* __restrict__ x4 = (const float4*)(x + base);
    const float4* __restrict__ y4 = (const float4*)(y + base);

    #pragma unroll
    for (int half = 0; half < 2; ++half) {
        float4 xv[4], yv[4];
        #pragma unroll
        for (int k = 0; k < 4; ++k) {
            int i = tid + (half * 4 + k) * 256;
            xv[k] = x4[i];
            yv[k] = y4[i];
        }
        #pragma unroll
        for (int k = 0; k < 4; ++k) {
            #pragma unroll
            for (int c = 0; c < 4; ++c) {
                float v = __fadd_rn(__fmul_rn((&xv[k].x)[c], 64.0f), (&yv[k].x)[c]);
                int idx = (int)v;
                if (idx > NB - 1) idx = NB - 1;
                asm volatile("" :: "v"(v), "v"(idx));
            }
        }
    }
}

// ABLATION 2: no loads, synthetic indices, same ds_add count + reduction.
// Measures the pure LDS-atomic floor. Writes to hist2 (separate ws region).
__global__ __launch_bounds__(256) void mi_ablate_atomic(unsigned int* __restrict__ hist2) {
    __shared__ unsigned int lh[4][NB / 2][64];
    __shared__ unsigned int rb[4][NB];

    const int tid  = threadIdx.x;
    const int wave = tid >> 6;
    const int lane = tid & 63;

    for (int i = tid; i < 4 * (NB / 2) * 64 + 4 * NB; i += 256)
        ((unsigned int*)lh)[i] = 0u;
    __syncthreads();

    unsigned int* __restrict__ myrow = &lh[wave][0][lane];
    unsigned int h = (unsigned int)(tid * 40503u + blockIdx.x * 12345u);

    #pragma unroll 4
    for (int i = 0; i < 32; ++i) {           // 32 elements/thread, same as hist
        h = h * 2654435761u + 12345u;
        unsigned int idx = h >> 26;          // 6 bits -> 0..63
        atomicAdd(myrow + (idx >> 1) * 64, 1u << ((idx & 1) << 4));
    }
    __syncthreads();

    if (lane < 32) {
        unsigned int lo = 0, hi = 0;
        #pragma unroll
        for (int j = 0; j < 64; ++j) {
            unsigned int vv = lh[wave][lane][(j + lane) & 63];
            lo += vv & 0xffffu;
            hi += vv >> 16;
        }
        rb[wave][2 * lane]     = lo;
        rb[wave][2 * lane + 1] = hi;
    }
    __syncthreads();

    if (tid < NB)
        atomicAdd(&hist2[blockIdx.y * NB + tid],
                  rb[0][tid] + rb[1][tid] + rb[2][tid] + rb[3][tid]);
}

// One block: 16 waves, wave b handles batch b, lane k handles bin k.
__global__ __launch_bounds__(1024) void mi_final_kernel(const unsigned int* __restrict__ hist,
                                                        float* __restrict__ out) {
    const int tid = threadIdx.x;
    const int b   = tid >> 6;
    const int k   = tid & 63;

    float h = (float)hist[b * NB + k];

    float s = h;
    #pragma unroll
    for (int off = 32; off >= 1; off >>= 1) s += __shfl_xor(s, off, 64);

    float jp = h / s + EPS;

    float p = jp;
    #pragma unroll
    for (int off = 32; off >= 1; off >>= 1) p += __shfl_xor(p, off, 64);

    float term = jp * logf(jp / (p * p));
    float t = term;
    #pragma unroll
    for (int off = 32; off >= 1; off >>= 1) t += __shfl_xor(t, off, 64);

    __shared__ float mi[BATCHES];
    if (k == 0) mi[b] = t;
    __syncthreads();

    if (tid == 0) {
        float acc = 0.0f;
        #pragma unroll
        for (int i = 0; i < BATCHES; ++i) acc += mi[i];
        *out = -acc / (float)BATCHES;
    }
}

extern "C" void kernel_launch(void* const* d_in, const int* in_sizes, int n_in,
                              void* d_out, int out_size, void* d_ws, size_t ws_size,
                              hipStream_t stream) {
    const float* x = (const float*)d_in[0];
    const float* y = (const float*)d_in[1];
    float* out = (float*)d_out;
    unsigned int* hist  = (unsigned int*)d_ws;
    unsigned int* hist2 = hist + BATCHES * NB;

    mi_zero_kernel<<<1, 1024, 0, stream>>>(hist);

    dim3 grid(CHUNKS, BATCHES);
    mi_hist_kernel<<<grid, 256, 0, stream>>>(x, y, hist);

    mi_final_kernel<<<1, 1024, 0, stream>>>(hist, out);

    // Diagnostic ablations (run after `out` is produced; do not touch it).
    if (ws_size >= 2 * BATCHES * NB * sizeof(unsigned int)) {
        mi_ablate_loads<<<grid, 256, 0, stream>>>(x, y);
        mi_ablate_atomic<<<grid, 256, 0, stream>>>(hist2);
    }
}